// Round 4
// baseline (144.808 us; speedup 1.0000x reference)
//
#include <hip/hip_runtime.h>
#include <stdint.h>

// WassersteinLoss: out = scale * sum_{b,c,t} |a-b| * (T - t)
// R3: stream reads through global_load_lds DMA (bypasses VGPR return path /
// L1 MSHR cap that pinned vector-load kernels at ~5.4 B/cyc/CU). Each block
// stages 16KB of a + 16KB of b per iteration into LDS, consumes via
// stride-1 float4 LDS reads. 1024 blocks = 4 resident/CU for drain overlap.

#define T_MASK 8191
#define T_DIMF 8192.0f

// per block: 16384 floats per array, in 4 iterations of 4096 floats (16 KB)
#define FLOATS_PER_BLOCK 16384
#define CHUNK_FLOATS 4096
#define NITER (FLOATS_PER_BLOCK / CHUNK_FLOATS)

__device__ __forceinline__ void load_lds16(const float* g, float* l) {
    __builtin_amdgcn_global_load_lds(
        (const __attribute__((address_space(1))) void*)g,
        (__attribute__((address_space(3))) void*)l,
        16 /*bytes per lane*/, 0 /*offset*/, 0 /*aux*/);
}

__global__ __launch_bounds__(256)
void wl_partial_kernel(const float* __restrict__ a,
                       const float* __restrict__ b,
                       float* __restrict__ partial) {
    __shared__ float ldsA[CHUNK_FLOATS];
    __shared__ float ldsB[CHUNK_FLOATS];

    const int tid  = threadIdx.x;
    const int lane = tid & 63;
    const int wave = tid >> 6;              // 0..3
    const int blockBase = blockIdx.x * FLOATS_PER_BLOCK;

    float acc = 0.0f;

    for (int it = 0; it < NITER; ++it) {
        const int chunkBase = blockBase + it * CHUNK_FLOATS;

        // Stage: each wave DMAs its 1024-float segment of each array,
        // 4 stages x (64 lanes x 16 B). LDS dest = wave-uniform base;
        // HW scatters lane i to base + 16*i. Global layout == LDS layout.
        #pragma unroll
        for (int s = 0; s < 4; ++s) {
            const int seg = wave * 1024 + s * 256;        // float offset, wave-uniform
            const int g   = chunkBase + seg + lane * 4;   // per-lane float index
            load_lds16(a + g, &ldsA[seg]);
            load_lds16(b + g, &ldsB[seg]);
        }
        __syncthreads();   // compiler emits s_waitcnt vmcnt(0) before s_barrier

        // Consume: 4 float4 per thread per array, stride-1 across lanes.
        #pragma unroll
        for (int k = 0; k < 4; ++k) {
            const int f4 = tid + k * 256;                 // float4 index in chunk
            float4 x = ((const float4*)ldsA)[f4];
            float4 y = ((const float4*)ldsB)[f4];
            const int g = chunkBase + f4 * 4;             // global float index of .x
            float w = T_DIMF - (float)(g & T_MASK);       // weight of .x; 4|T so no wrap
            float d0 = fabsf(x.x - y.x);
            float d1 = fabsf(x.y - y.y);
            float d2 = fabsf(x.z - y.z);
            float d3 = fabsf(x.w - y.w);
            acc += w * (d0 + d1 + d2 + d3) - (d1 + 2.0f * d2 + 3.0f * d3);
        }
        __syncthreads();   // protect LDS reuse next iteration
    }

    // wave-64 shuffle reduction
    #pragma unroll
    for (int off = 32; off > 0; off >>= 1)
        acc += __shfl_down(acc, off, 64);

    __shared__ float wave_sums[4];
    if (lane == 0) wave_sums[wave] = acc;
    __syncthreads();

    if (tid == 0)
        partial[blockIdx.x] = wave_sums[0] + wave_sums[1] + wave_sums[2] + wave_sums[3];
}

__global__ __launch_bounds__(256)
void wl_final_kernel(const float* __restrict__ partial, int n,
                     float* __restrict__ out, float scale) {
    float acc = 0.0f;
    for (int i = threadIdx.x; i < n; i += 256)
        acc += partial[i];

    #pragma unroll
    for (int off = 32; off > 0; off >>= 1)
        acc += __shfl_down(acc, off, 64);

    __shared__ float wave_sums[4];
    int lane = threadIdx.x & 63;
    int wave = threadIdx.x >> 6;
    if (lane == 0) wave_sums[wave] = acc;
    __syncthreads();

    if (threadIdx.x == 0)
        out[0] = (wave_sums[0] + wave_sums[1] + wave_sums[2] + wave_sums[3]) * scale;
}

extern "C" void kernel_launch(void* const* d_in, const int* in_sizes, int n_in,
                              void* d_out, int out_size, void* d_ws, size_t ws_size,
                              hipStream_t stream) {
    const float* a = (const float*)d_in[0];
    const float* b = (const float*)d_in[1];
    float* out = (float*)d_out;
    float* partial = (float*)d_ws;

    int n = in_sizes[0];                     // 16,777,216
    int blocks = n / FLOATS_PER_BLOCK;       // 1024

    const long long T = 8192;
    const long long C = 64;
    const long long B = (long long)n / (C * T);
    float scale = (float)(2.0 / ((double)T * (double)C * (double)(T + 1) * (double)B));

    wl_partial_kernel<<<blocks, 256, 0, stream>>>(a, b, partial);
    wl_final_kernel<<<1, 256, 0, stream>>>(partial, blocks, out, scale);
}